// Round 10
// baseline (2974.272 us; speedup 1.0000x reference)
//
#include <hip/hip_runtime.h>
#include <cstddef>

constexpr int B_ = 8;
constexpr int N_ = 8192;
constexpr int NPOINT_ = 2048;
constexpr int NSAMPLE_ = 32;
constexpr int DIN_ = 32;
constexpr int C1_ = 64;
constexpr int C2_ = 128;
constexpr float EPS_ = 1e-5f;
constexpr int TOT_ = B_ * NPOINT_ * NSAMPLE_;  // 524288

typedef __attribute__((ext_vector_type(2))) float f32x2;

// ---------------------------------------------------------------------------
// K1: fused FPS + feature transpose. Blocks 0-7: farthest point sampling (one
// per batch, 512 threads, 16 pts/thread). Blocks 8+: grid-stride transpose of
// points (B,32,N) -> featT (B,N,32) on the 248 otherwise-idle CUs.
// FPS distance math is packed fp32 (v_pk_add/mul_f32: 2 points/instr, the
// 2x-rate path implied by gfx950's 157 TF fp32 spec). x-c computed as
// x + (-c) (IEEE-identical). Min/argmax in C (pd is data-dependent ->
// non-rematerializable -> register-resident). Cross-wave reduce = lane0
// atomicMax into step-tagged monotone u64 slot (dbuf), barrier, 1 read.
// Bit-exact numpy semantics: RN ops, left-to-right sum, first-index tie-break.
// ---------------------------------------------------------------------------
#define FT 512
__global__ __attribute__((amdgpu_waves_per_eu(2, 2)))
__launch_bounds__(FT) void k_fps_tr(const float* __restrict__ xyz,
                                    const float* __restrict__ pts,
                                    float* __restrict__ featT,
                                    float* __restrict__ nxT,
                                    float* __restrict__ out0) {
  const int tid = threadIdx.x;

  __shared__ float4 cP[N_];                      // 128 KB coord copy (fps)
  __shared__ unsigned long long slot[2];
  __shared__ float tile[DIN_][64 + 1];           // transpose staging

  if (blockIdx.x >= 8) {
    // ---- transpose path: 1024 jobs of 64 columns, grid-stride
    for (int bn = (int)blockIdx.x - 8; bn < B_ * (N_ / 64); bn += (int)gridDim.x - 8) {
      const int b = bn >> 7;                     // / (N/64 = 128)
      const int n0 = (bn & 127) * 64;
      __syncthreads();
#pragma unroll
      for (int i = 0; i < 4; i++) {
        const int id = i * 512 + tid;
        const int c = id >> 6, nn = id & 63;
        tile[c][nn] = pts[((size_t)b * DIN_ + c) * N_ + n0 + nn];
      }
      __syncthreads();
#pragma unroll
      for (int i = 0; i < 4; i++) {
        const int id = i * 512 + tid;
        const int nn = id >> 5, c = id & 31;
        featT[((size_t)(b * N_ + n0 + nn)) * DIN_ + c] = tile[c][nn];
      }
    }
    return;
  }

  // ---- fps path
  const int b = blockIdx.x;
  const int lane = tid & 63;
  const float* xb = xyz + (size_t)b * 3 * N_;

#define DECLP(k)                                                    \
  f32x2 X##k, Y##k, Z##k;                                           \
  X##k.x = xb[tid + (2 * k) * FT];                                  \
  X##k.y = xb[tid + (2 * k + 1) * FT];                              \
  Y##k.x = xb[N_ + tid + (2 * k) * FT];                             \
  Y##k.y = xb[N_ + tid + (2 * k + 1) * FT];                         \
  Z##k.x = xb[2 * N_ + tid + (2 * k) * FT];                         \
  Z##k.y = xb[2 * N_ + tid + (2 * k + 1) * FT];                     \
  float pDa##k = 1e10f, pDb##k = 1e10f;
  DECLP(0) DECLP(1) DECLP(2) DECLP(3) DECLP(4) DECLP(5) DECLP(6) DECLP(7)
#undef DECLP

#define FILLP(k)                                                            \
  cP[tid + (2 * k) * FT] = make_float4(X##k.x, Y##k.x, Z##k.x, 0.f);        \
  cP[tid + (2 * k + 1) * FT] = make_float4(X##k.y, Y##k.y, Z##k.y, 0.f);
  FILLP(0) FILLP(1) FILLP(2) FILLP(3) FILLP(4) FILLP(5) FILLP(6) FILLP(7)
#undef FILLP

  // Pin coordinate pairs (opaque -> no remat/sink; R3-R5 lesson).
  asm volatile("" : "+v"(X0), "+v"(X1), "+v"(X2), "+v"(X3),
                    "+v"(X4), "+v"(X5), "+v"(X6), "+v"(X7));
  asm volatile("" : "+v"(Y0), "+v"(Y1), "+v"(Y2), "+v"(Y3),
                    "+v"(Y4), "+v"(Y5), "+v"(Y6), "+v"(Y7));
  asm volatile("" : "+v"(Z0), "+v"(Z1), "+v"(Z2), "+v"(Z3),
                    "+v"(Z4), "+v"(Z5), "+v"(Z6), "+v"(Z7));

  if (tid == 0) { slot[0] = 0ull; slot[1] = 0ull; }
  __syncthreads();

// packed distance for pair k (points 2k, 2k+1):
// d = ((x-cx)^2 + (y-cy)^2) + (z-cz)^2, both halves, RN, left-to-right.
#define PKD(k)                                                      \
  "v_pk_add_f32 %[t0], %[x" #k "], %[nx]\n\t"                       \
  "v_pk_add_f32 %[t1], %[y" #k "], %[ny]\n\t"                       \
  "v_pk_add_f32 %[t2], %[z" #k "], %[nz]\n\t"                       \
  "v_pk_mul_f32 %[t0], %[t0], %[t0]\n\t"                            \
  "v_pk_mul_f32 %[t1], %[t1], %[t1]\n\t"                            \
  "v_pk_mul_f32 %[t2], %[t2], %[t2]\n\t"                            \
  "v_pk_add_f32 %[t0], %[t0], %[t1]\n\t"                            \
  "v_pk_add_f32 %[d" #k "], %[t0], %[t2]\n\t"

// scalar min + first-index argmax (ascending j, strict > keeps first max)
#define PROC(jj, val, pdv)                                          \
  {                                                                 \
    const float nd = fminf(pdv, (val));                             \
    pdv = nd;                                                       \
    if (nd > lv) { lv = nd; js = (jj); }                            \
  }

  int far = 0;
  int h0 = 0, h1 = 0, h2 = 0, h3 = 0;  // far-at-entry of steps tid+k*512
  for (int s = 0; s < NPOINT_ - 1; ++s) {
    const float4 c = cP[far];                    // one b128 broadcast read
    f32x2 ncx, ncy, ncz;
    ncx.x = -c.x; ncx.y = -c.x;
    ncy.x = -c.y; ncy.y = -c.y;
    ncz.x = -c.z; ncz.y = -c.z;

    f32x2 d0, d1, d2, d3, d4, d5, d6, d7, t0, t1, t2;
    asm volatile(
        PKD(0) PKD(1) PKD(2) PKD(3) PKD(4) PKD(5) PKD(6) PKD(7)
        : [d0] "=&v"(d0), [d1] "=&v"(d1), [d2] "=&v"(d2), [d3] "=&v"(d3),
          [d4] "=&v"(d4), [d5] "=&v"(d5), [d6] "=&v"(d6), [d7] "=&v"(d7),
          [t0] "=&v"(t0), [t1] "=&v"(t1), [t2] "=&v"(t2)
        : [x0] "v"(X0), [y0] "v"(Y0), [z0] "v"(Z0),
          [x1] "v"(X1), [y1] "v"(Y1), [z1] "v"(Z1),
          [x2] "v"(X2), [y2] "v"(Y2), [z2] "v"(Z2),
          [x3] "v"(X3), [y3] "v"(Y3), [z3] "v"(Z3),
          [x4] "v"(X4), [y4] "v"(Y4), [z4] "v"(Z4),
          [x5] "v"(X5), [y5] "v"(Y5), [z5] "v"(Z5),
          [x6] "v"(X6), [y6] "v"(Y6), [z6] "v"(Z6),
          [x7] "v"(X7), [y7] "v"(Y7), [z7] "v"(Z7),
          [nx] "v"(ncx), [ny] "v"(ncy), [nz] "v"(ncz));

    float lv = 0.0f;
    int js = 0;
    PROC(0, d0.x, pDa0)  PROC(1, d0.y, pDb0)
    PROC(2, d1.x, pDa1)  PROC(3, d1.y, pDb1)
    PROC(4, d2.x, pDa2)  PROC(5, d2.y, pDb2)
    PROC(6, d3.x, pDa3)  PROC(7, d3.y, pDb3)
    PROC(8, d4.x, pDa4)  PROC(9, d4.y, pDb4)
    PROC(10, d5.x, pDa5) PROC(11, d5.y, pDb5)
    PROC(12, d6.x, pDa6) PROC(13, d6.y, pDb6)
    PROC(14, d7.x, pDa7) PROC(15, d7.y, pDb7)
    const int li = tid + (js << 9);

    // pack: [55:45]=step (monotone -> no slot reset), [44:13]=dist bits
    // (nonneg f32, order-preserving), [12:0]=8191-idx (min index wins).
    unsigned long long pk = ((unsigned long long)s << 45) |
                            (((unsigned long long)__float_as_uint(lv)) << 13) |
                            (unsigned)(8191 - li);
#pragma unroll
    for (int off = 1; off < 64; off <<= 1) {
      const unsigned long long o = __shfl_xor(pk, off);
      pk = (o > pk) ? o : pk;
    }
    if (lane == 0) atomicMax(&slot[s & 1], pk);
    __syncthreads();
    far = 8191 - (int)(slot[s & 1] & 0x1FFFull);

    const int d = s + 1 - tid;
    if (d == 0) h0 = far;
    if (d == 512) h1 = far;
    if (d == 1024) h2 = far;
    if (d == 1536) h3 = far;
  }
#undef PKD
#undef PROC

  // epilogue: thread t writes centroids for steps t, t+512, t+1024, t+1536
  {
#define WOUT(k, hh)                                                   \
    {                                                                 \
      const int ss = tid + (k) * FT;                                  \
      const float4 cc = cP[hh];                                       \
      nxT[(size_t)(b * NPOINT_ + ss) * 3 + 0] = cc.x;                 \
      nxT[(size_t)(b * NPOINT_ + ss) * 3 + 1] = cc.y;                 \
      nxT[(size_t)(b * NPOINT_ + ss) * 3 + 2] = cc.z;                 \
      out0[((size_t)b * 3 + 0) * NPOINT_ + ss] = cc.x;                \
      out0[((size_t)b * 3 + 1) * NPOINT_ + ss] = cc.y;                \
      out0[((size_t)b * 3 + 2) * NPOINT_ + ss] = cc.z;                \
    }
    WOUT(0, h0) WOUT(1, h1) WOUT(2, h2) WOUT(3, h3)
#undef WOUT
  }
}

// ---------------------------------------------------------------------------
// K2: ball query. One wave per centroid; first 32 in-radius indices in
// ascending index order via ballot ranks, early exit, pad with first.
// ---------------------------------------------------------------------------
__global__ __launch_bounds__(256) void k_ballquery(const float* __restrict__ xyz,
                                                   const float* __restrict__ nxT,
                                                   int* __restrict__ gidx) {
  const int wid = (int)((blockIdx.x * 256 + threadIdx.x) >> 6);
  const int lane = threadIdx.x & 63;
  const int b = wid >> 11;                 // / NPOINT
  const float* xb = xyz + (size_t)b * 3 * N_;
  const float cx = nxT[(size_t)wid * 3 + 0];
  const float cy = nxT[(size_t)wid * 3 + 1];
  const float cz = nxT[(size_t)wid * 3 + 2];
  int* out = gidx + (size_t)wid * NSAMPLE_;

  int count = 0, first = 0;
  for (int ch = 0; ch < N_ / 64; ++ch) {
    const int j = ch * 64 + lane;
    const float dx = xb[j] - cx, dy = xb[N_ + j] - cy, dz = xb[2 * N_ + j] - cz;
    const float d2 = __fadd_rn(__fadd_rn(__fmul_rn(dx, dx), __fmul_rn(dy, dy)),
                               __fmul_rn(dz, dz));
    const bool in = (d2 <= 0.16f);         // 0.16f == f32(0.4*0.4), exact match
    const unsigned long long mask = __ballot(in);
    if (mask) {
      if (count == 0) first = ch * 64 + (__ffsll((long long)mask) - 1);
      if (in) {
        const int rank = count + __popcll(mask & ((1ull << lane) - 1ull));
        if (rank < NSAMPLE_) out[rank] = j;
      }
      count += __popcll(mask);
      if (count >= NSAMPLE_) break;
    }
  }
  if (count < NSAMPLE_ && lane >= count && lane < NSAMPLE_) out[lane] = first;
}

// ---------------------------------------------------------------------------
// K3/K5: gather + MLP, software-pipelined: group i+1's gather is issued into
// REGISTERS while group i computes (T14 async-stage); gidx read directly per
// thread (L1 broadcast).
// PHASE 1: layer-1 partial BN stats. PHASE 2: layer-1 (folded BN) + layer-2;
// emits layer-2 partial BN stats AND per-(group,channel) max/min of raw y2
// (max-pool commutes with the monotone affine+relu epilogue).
// ---------------------------------------------------------------------------
template <int PHASE>
__global__ __launch_bounds__(256) void k_mlp(
    const float* __restrict__ xyz, const float* __restrict__ featT,
    const float* __restrict__ nxT, const int* __restrict__ gidx,
    const float* __restrict__ w1, const float* __restrict__ b1,
    const float* __restrict__ w2, const float* __restrict__ b2,
    const float* __restrict__ ac1,
    float* __restrict__ part, float* __restrict__ maxb, float* __restrict__ minb) {
  __shared__ float xs[32][36];
  __shared__ float w1s[64 * 35];
  __shared__ __align__(16) float w2cm[64 * 128];  // c-major [c][o]
  __shared__ __align__(16) float x2s[32 * 64];
  __shared__ float pbuf[2048];

  const int t = threadIdx.x;
  for (int i = t; i < 64 * 35; i += 256) w1s[i] = w1[i];
  if constexpr (PHASE == 2) {
    for (int i = t; i < 64 * 128; i += 256) {
      const int c = i >> 7, o = i & 127;
      w2cm[i] = w2[o * 64 + c];
    }
  }
  const int o2 = t & 31, kq = t >> 5;
  const int gk = t >> 3, gq = t & 7;   // gather: sample gk, float4 slot gq

  float bb1[2];
  float a1r[2] = {0.f, 0.f}, c1r[2] = {0.f, 0.f};
  float bb2[4] = {0.f, 0.f, 0.f, 0.f};
#pragma unroll
  for (int q = 0; q < 2; q++) bb1[q] = b1[o2 * 2 + q];
  if constexpr (PHASE == 2) {
#pragma unroll
    for (int q = 0; q < 2; q++) { a1r[q] = ac1[o2 * 2 + q]; c1r[q] = ac1[64 + o2 * 2 + q]; }
#pragma unroll
    for (int q = 0; q < 4; q++) bb2[q] = b2[o2 * 4 + q];
  }

  float s1a[2] = {0.f, 0.f}, s1q[2] = {0.f, 0.f};
  float s2a[4] = {0.f, 0.f, 0.f, 0.f}, s2q[4] = {0.f, 0.f, 0.f, 0.f};

  // ---- prologue: stage group 0 into registers
  float4 fpre;
  float xpx = 0.f, xpy = 0.f, xpz = 0.f;
  {
    const int G = blockIdx.x * 8;
    const int b = G >> 11;
    const int j = gidx[(size_t)G * NSAMPLE_ + gk];
    fpre = *(const float4*)(featT + ((size_t)(b * N_ + j)) * DIN_ + gq * 4);
    if (t < 32) {
      const int j2 = gidx[(size_t)G * NSAMPLE_ + t];
      const float* xb = xyz + (size_t)b * 3 * N_;
      xpx = xb[j2] - nxT[(size_t)G * 3 + 0];
      xpy = xb[N_ + j2] - nxT[(size_t)G * 3 + 1];
      xpz = xb[2 * N_ + j2] - nxT[(size_t)G * 3 + 2];
    }
  }

  for (int i = 0; i < 8; i++) {
    const int G = blockIdx.x * 8 + i;
    __syncthreads();   // xs free (previous group's compute done)
    // commit staged registers -> LDS
    xs[gk][3 + gq * 4 + 0] = fpre.x;
    xs[gk][3 + gq * 4 + 1] = fpre.y;
    xs[gk][3 + gq * 4 + 2] = fpre.z;
    xs[gk][3 + gq * 4 + 3] = fpre.w;
    if (t < 32) { xs[t][0] = xpx; xs[t][1] = xpy; xs[t][2] = xpz; }
    // issue next group's gather (overlaps this group's compute)
    if (i < 7) {
      const int Gn = G + 1;
      const int bn = Gn >> 11;
      const int jn = gidx[(size_t)Gn * NSAMPLE_ + gk];
      fpre = *(const float4*)(featT + ((size_t)(bn * N_ + jn)) * DIN_ + gq * 4);
      if (t < 32) {
        const int j2 = gidx[(size_t)Gn * NSAMPLE_ + t];
        const float* xb = xyz + (size_t)bn * 3 * N_;
        xpx = xb[j2] - nxT[(size_t)Gn * 3 + 0];
        xpy = xb[N_ + j2] - nxT[(size_t)Gn * 3 + 1];
        xpz = xb[2 * N_ + j2] - nxT[(size_t)Gn * 3 + 2];
      }
    }
    __syncthreads();

    // layer 1: y1[k][o], thread tile 4k x 2o
    float acc[4][2];
#pragma unroll
    for (int r = 0; r < 4; r++) { acc[r][0] = bb1[0]; acc[r][1] = bb1[1]; }
#pragma unroll
    for (int c = 0; c < 35; c++) {
      float xv[4];
#pragma unroll
      for (int r = 0; r < 4; r++) xv[r] = xs[kq * 4 + r][c];
      float wv[2];
      wv[0] = w1s[(o2 * 2 + 0) * 35 + c];
      wv[1] = w1s[(o2 * 2 + 1) * 35 + c];
#pragma unroll
      for (int r = 0; r < 4; r++) { acc[r][0] += xv[r] * wv[0]; acc[r][1] += xv[r] * wv[1]; }
    }

    if constexpr (PHASE == 1) {
#pragma unroll
      for (int q = 0; q < 2; q++)
#pragma unroll
        for (int r = 0; r < 4; r++) {
          const float v = acc[r][q];
          s1a[q] += v;
          s1q[q] += v * v;
        }
    } else {
#pragma unroll
      for (int r = 0; r < 4; r++)
#pragma unroll
        for (int q = 0; q < 2; q++) {
          float v = acc[r][q] * a1r[q] + c1r[q];
          v = fmaxf(v, 0.f);
          x2s[(kq * 4 + r) * 64 + o2 * 2 + q] = v;
        }
      __syncthreads();

      // layer 2: y2[k][o], thread tile 4k x 4o, float4 LDS reads
      float a2[4][4];
#pragma unroll
      for (int r = 0; r < 4; r++)
#pragma unroll
        for (int q = 0; q < 4; q++) a2[r][q] = bb2[q];
#pragma unroll 4
      for (int cc4 = 0; cc4 < 16; cc4++) {
        float4 xv4[4];
#pragma unroll
        for (int r = 0; r < 4; r++) xv4[r] = *(const float4*)&x2s[(kq * 4 + r) * 64 + cc4 * 4];
        float4 wv4[4];
#pragma unroll
        for (int cq = 0; cq < 4; cq++) wv4[cq] = *(const float4*)&w2cm[(cc4 * 4 + cq) * 128 + o2 * 4];
#pragma unroll
        for (int cq = 0; cq < 4; cq++) {
#pragma unroll
          for (int r = 0; r < 4; r++) {
            const float xr = ((const float*)&xv4[r])[cq];
#pragma unroll
            for (int q = 0; q < 4; q++) a2[r][q] += xr * ((const float*)&wv4[cq])[q];
          }
        }
      }

      // BN2 stats
#pragma unroll
      for (int q = 0; q < 4; q++)
#pragma unroll
        for (int r = 0; r < 4; r++) {
          const float v = a2[r][q];
          s2a[q] += v;
          s2q[q] += v * v;
        }
      // per-group max/min of raw y2 over the 32 samples
      float mx[4], mn[4];
#pragma unroll
      for (int q = 0; q < 4; q++) { mx[q] = a2[0][q]; mn[q] = a2[0][q]; }
#pragma unroll
      for (int r = 1; r < 4; r++)
#pragma unroll
        for (int q = 0; q < 4; q++) {
          mx[q] = fmaxf(mx[q], a2[r][q]);
          mn[q] = fminf(mn[q], a2[r][q]);
        }
#pragma unroll
      for (int q = 0; q < 4; q++) {
        pbuf[kq * 128 + o2 * 4 + q] = mx[q];
        pbuf[1024 + kq * 128 + o2 * 4 + q] = mn[q];
      }
      __syncthreads();
      if (t < 128) {
        float MX = pbuf[t], MN = pbuf[1024 + t];
#pragma unroll
        for (int kk = 1; kk < 8; kk++) {
          MX = fmaxf(MX, pbuf[kk * 128 + t]);
          MN = fminf(MN, pbuf[1024 + kk * 128 + t]);
        }
        maxb[(size_t)G * 128 + t] = MX;
        minb[(size_t)G * 128 + t] = MN;
      }
    }
  }

  // deterministic block-level stat dump
  if constexpr (PHASE == 1) {
    __syncthreads();
#pragma unroll
    for (int q = 0; q < 2; q++) {
      pbuf[(o2 * 2 + q) * 8 + kq] = s1a[q];
      pbuf[512 + (o2 * 2 + q) * 8 + kq] = s1q[q];
    }
    __syncthreads();
    if (t < 64) {
      float S = 0.f, Q = 0.f;
#pragma unroll
      for (int kk = 0; kk < 8; kk++) { S += pbuf[t * 8 + kk]; Q += pbuf[512 + t * 8 + kk]; }
      part[(size_t)blockIdx.x * 128 + t * 2 + 0] = S;
      part[(size_t)blockIdx.x * 128 + t * 2 + 1] = Q;
    }
  }
  if constexpr (PHASE == 2) {
    __syncthreads();
#pragma unroll
    for (int q = 0; q < 4; q++) {
      pbuf[(o2 * 4 + q) * 8 + kq] = s2a[q];
      pbuf[1024 + (o2 * 4 + q) * 8 + kq] = s2q[q];
    }
    __syncthreads();
    if (t < 128) {
      float S = 0.f, Q = 0.f;
#pragma unroll
      for (int kk = 0; kk < 8; kk++) { S += pbuf[t * 8 + kk]; Q += pbuf[1024 + t * 8 + kk]; }
      part[(size_t)blockIdx.x * 256 + t * 2 + 0] = S;
      part[(size_t)blockIdx.x * 256 + t * 2 + 1] = Q;
    }
  }
}

// ---------------------------------------------------------------------------
// K4/K6: reduce block partials -> BN scale/bias. 1024 threads.
// Fixed-order (deterministic).
// ---------------------------------------------------------------------------
__global__ __launch_bounds__(1024) void k_stats1(const float* __restrict__ part,
                                                 const float* __restrict__ g,
                                                 const float* __restrict__ be,
                                                 float* __restrict__ ac) {
  const int t = threadIdx.x;
  const int ch = t & 63, sl = t >> 6;  // 16 slices
  float s = 0.f, q = 0.f;
  for (int bk = sl; bk < 2048; bk += 16) {
    s += part[(size_t)bk * 128 + ch * 2 + 0];
    q += part[(size_t)bk * 128 + ch * 2 + 1];
  }
  __shared__ float ss[16][64], qs[16][64];
  ss[sl][ch] = s;
  qs[sl][ch] = q;
  __syncthreads();
  if (t < 64) {
    float S = 0.f, Q = 0.f;
#pragma unroll
    for (int k = 0; k < 16; k++) { S += ss[k][t]; Q += qs[k][t]; }
    const float mu = S / (float)TOT_;
    const float var = Q / (float)TOT_ - mu * mu;
    const float a = g[t] * (1.0f / sqrtf(var + EPS_));
    ac[t] = a;
    ac[64 + t] = be[t] - mu * a;
  }
}

__global__ __launch_bounds__(1024) void k_stats2(const float* __restrict__ part,
                                                 const float* __restrict__ g,
                                                 const float* __restrict__ be,
                                                 float* __restrict__ ac) {
  const int t = threadIdx.x;
  const int ch = t & 127, sl = t >> 7;  // 8 slices
  float s = 0.f, q = 0.f;
  for (int bk = sl; bk < 2048; bk += 8) {
    s += part[(size_t)bk * 256 + ch * 2 + 0];
    q += part[(size_t)bk * 256 + ch * 2 + 1];
  }
  __shared__ float ss[8][128], qs[8][128];
  ss[sl][ch] = s;
  qs[sl][ch] = q;
  __syncthreads();
  if (t < 128) {
    float S = 0.f, Q = 0.f;
#pragma unroll
    for (int k = 0; k < 8; k++) { S += ss[k][t]; Q += qs[k][t]; }
    const float mu = S / (float)TOT_;
    const float var = Q / (float)TOT_ - mu * mu;
    const float a = g[t] * (1.0f / sqrtf(var + EPS_));
    ac[t] = a;
    ac[128 + t] = be[t] - mu * a;
  }
}

// ---------------------------------------------------------------------------
// K7: finalize. out1[b][ch][s] = relu(a2[ch]*(a2>=0 ? max : min) + c2[ch]).
// LDS transpose so both the minmax reads and the out1 writes are coalesced.
// ---------------------------------------------------------------------------
__global__ __launch_bounds__(256) void k_finalize(const float* __restrict__ maxb,
                                                  const float* __restrict__ minb,
                                                  const float* __restrict__ ac2,
                                                  float* __restrict__ out1) {
  __shared__ float tile[128][33];
  const int b = blockIdx.x >> 6;
  const int s0 = (blockIdx.x & 63) * 32;
  const int t = threadIdx.x;
#pragma unroll
  for (int it = 0; it < 16; ++it) {
    const int idx = it * 256 + t;
    const int sl = idx >> 7, ch = idx & 127;
    const size_t G = (size_t)b * NPOINT_ + s0 + sl;
    const float a = ac2[ch], c = ac2[128 + ch];
    const float y = (a >= 0.f) ? maxb[G * 128 + ch] : minb[G * 128 + ch];
    tile[ch][sl] = fmaxf(y * a + c, 0.f);
  }
  __syncthreads();
#pragma unroll
  for (int it = 0; it < 16; ++it) {
    const int idx = it * 256 + t;
    const int ch = idx >> 5, sl = idx & 31;
    out1[((size_t)(b * C2_ + ch)) * NPOINT_ + s0 + sl] = tile[ch][sl];
  }
}

// ---------------------------------------------------------------------------
extern "C" void kernel_launch(void* const* d_in, const int* in_sizes, int n_in,
                              void* d_out, int out_size, void* d_ws, size_t ws_size,
                              hipStream_t stream) {
  const float* xyz = (const float*)d_in[0];
  const float* pts = (const float*)d_in[1];
  const float* w1 = (const float*)d_in[2];
  const float* b1 = (const float*)d_in[3];
  const float* g1 = (const float*)d_in[4];
  const float* be1 = (const float*)d_in[5];
  const float* w2 = (const float*)d_in[6];
  const float* b2 = (const float*)d_in[7];
  const float* g2 = (const float*)d_in[8];
  const float* be2 = (const float*)d_in[9];

  float* out0 = (float*)d_out;
  float* out1 = out0 + (size_t)B_ * 3 * NPOINT_;

  float* wsf = (float*)d_ws;
  float* featT = wsf;                                    // B*N*32 = 2097152
  float* nxT = featT + (size_t)B_ * N_ * DIN_;           // B*NPOINT*3 = 49152
  float* part1 = nxT + (size_t)B_ * NPOINT_ * 3;         // 2048*128
  float* part2 = part1 + (size_t)2048 * 128;             // 2048*256
  float* ac1 = part2 + (size_t)2048 * 256;               // 128
  float* ac2 = ac1 + 128;                                // 256
  float* maxb = ac2 + 256;                               // 16384*128
  float* minb = maxb + (size_t)B_ * NPOINT_ * 128;       // 16384*128
  int* gidx = (int*)(minb + (size_t)B_ * NPOINT_ * 128); // B*NPOINT*32 ints

  k_fps_tr<<<dim3(256), dim3(FT), 0, stream>>>(xyz, pts, featT, nxT, out0);
  k_ballquery<<<dim3(B_ * NPOINT_ / 4), dim3(256), 0, stream>>>(xyz, nxT, gidx);
  k_mlp<1><<<dim3(2048), dim3(256), 0, stream>>>(xyz, featT, nxT, gidx, w1, b1, w2, b2,
                                                 nullptr, part1, nullptr, nullptr);
  k_stats1<<<dim3(1), dim3(1024), 0, stream>>>(part1, g1, be1, ac1);
  k_mlp<2><<<dim3(2048), dim3(256), 0, stream>>>(xyz, featT, nxT, gidx, w1, b1, w2, b2,
                                                 ac1, part2, maxb, minb);
  k_stats2<<<dim3(1), dim3(1024), 0, stream>>>(part2, g2, be2, ac2);
  k_finalize<<<dim3(B_ * (NPOINT_ / 32)), dim3(256), 0, stream>>>(maxb, minb, ac2, out1);
}

// Round 11
// 2041.070 us; speedup vs baseline: 1.4572x; 1.4572x over previous
//
#include <hip/hip_runtime.h>
#include <cstddef>

constexpr int B_ = 8;
constexpr int N_ = 8192;
constexpr int NPOINT_ = 2048;
constexpr int NSAMPLE_ = 32;
constexpr int DIN_ = 32;
constexpr int C1_ = 64;
constexpr int C2_ = 128;
constexpr float EPS_ = 1e-5f;
constexpr int TOT_ = B_ * NPOINT_ * NSAMPLE_;  // 524288

// ---------------------------------------------------------------------------
// K1: fused FPS + feature transpose. Blocks 0-7: FPS (one per batch, 512
// threads, 16 pts/thread, scalar asm distance path — R9-proven; v_pk_f32
// reverted, it is not a 2x path on CDNA4). Blocks 8+: grid-stride transpose.
// NEW: intra-wave reduction via single-instruction DPP max rounds
// (v_max_f32/u32 dst,dst,dst row_ror/bcast — 1 VALU op, ~4cyc, vs the u64
// bpermute butterfly's ~700cyc serial chain), then lane-63 step-tagged
// monotone u64 LDS atomicMax (double-buffered slot: race-free), barrier,
// one broadcast read. Exactness: max/compare only; f32 max == u32 max for
// nonneg; ties resolve to min index via max(8191-li).
// ---------------------------------------------------------------------------
#define FT 512
__global__ __attribute__((amdgpu_waves_per_eu(2, 2)))
__launch_bounds__(FT) void k_fps_tr(const float* __restrict__ xyz,
                                    const float* __restrict__ pts,
                                    float* __restrict__ featT,
                                    float* __restrict__ nxT,
                                    float* __restrict__ out0) {
  const int tid = threadIdx.x;

  __shared__ float4 cP[N_];                      // 128 KB coord copy (fps)
  __shared__ unsigned long long slot[2];
  __shared__ float tile[DIN_][64 + 1];           // transpose staging

  if (blockIdx.x >= 8) {
    // ---- transpose path: 1024 jobs of 64 columns, grid-stride
    for (int bn = (int)blockIdx.x - 8; bn < B_ * (N_ / 64); bn += (int)gridDim.x - 8) {
      const int b = bn >> 7;                     // / (N/64 = 128)
      const int n0 = (bn & 127) * 64;
      __syncthreads();
#pragma unroll
      for (int i = 0; i < 4; i++) {
        const int id = i * 512 + tid;
        const int c = id >> 6, nn = id & 63;
        tile[c][nn] = pts[((size_t)b * DIN_ + c) * N_ + n0 + nn];
      }
      __syncthreads();
#pragma unroll
      for (int i = 0; i < 4; i++) {
        const int id = i * 512 + tid;
        const int nn = id >> 5, c = id & 31;
        featT[((size_t)(b * N_ + n0 + nn)) * DIN_ + c] = tile[c][nn];
      }
    }
    return;
  }

  // ---- fps path
  const int b = blockIdx.x;
  const int lane = tid & 63;
  const float* xb = xyz + (size_t)b * 3 * N_;

#define DECL(j)                                   \
  float pX##j = xb[tid + j * FT];                 \
  float pY##j = xb[N_ + tid + j * FT];            \
  float pZ##j = xb[2 * N_ + tid + j * FT];        \
  float pD##j = 1e10f;
  DECL(0) DECL(1) DECL(2) DECL(3) DECL(4) DECL(5) DECL(6) DECL(7)
  DECL(8) DECL(9) DECL(10) DECL(11) DECL(12) DECL(13) DECL(14) DECL(15)
#undef DECL

#define FILL(j) cP[tid + j * FT] = make_float4(pX##j, pY##j, pZ##j, 0.f);
  FILL(0) FILL(1) FILL(2) FILL(3) FILL(4) FILL(5) FILL(6) FILL(7)
  FILL(8) FILL(9) FILL(10) FILL(11) FILL(12) FILL(13) FILL(14) FILL(15)
#undef FILL

  // Pin: make coordinate values opaque so they cannot be rematerialized.
  asm volatile("" : "+v"(pX0), "+v"(pY0), "+v"(pZ0), "+v"(pX1), "+v"(pY1), "+v"(pZ1),
                    "+v"(pX2), "+v"(pY2), "+v"(pZ2), "+v"(pX3), "+v"(pY3), "+v"(pZ3));
  asm volatile("" : "+v"(pX4), "+v"(pY4), "+v"(pZ4), "+v"(pX5), "+v"(pY5), "+v"(pZ5),
                    "+v"(pX6), "+v"(pY6), "+v"(pZ6), "+v"(pX7), "+v"(pY7), "+v"(pZ7));
  asm volatile("" : "+v"(pX8), "+v"(pY8), "+v"(pZ8), "+v"(pX9), "+v"(pY9), "+v"(pZ9),
                    "+v"(pX10), "+v"(pY10), "+v"(pZ10), "+v"(pX11), "+v"(pY11), "+v"(pZ11));
  asm volatile("" : "+v"(pX12), "+v"(pY12), "+v"(pZ12), "+v"(pX13), "+v"(pY13), "+v"(pZ13),
                    "+v"(pX14), "+v"(pY14), "+v"(pZ14), "+v"(pX15), "+v"(pY15), "+v"(pZ15));

  if (tid == 0) { slot[0] = 0ull; slot[1] = 0ull; }
  __syncthreads();

#define UPDASM(j)                                                   \
  "v_sub_f32 %[t0], %[px" #j "], %[cx]\n\t"                         \
  "v_sub_f32 %[t1], %[py" #j "], %[cy]\n\t"                         \
  "v_sub_f32 %[t2], %[pz" #j "], %[cz]\n\t"                         \
  "v_mul_f32 %[t0], %[t0], %[t0]\n\t"                               \
  "v_mul_f32 %[t1], %[t1], %[t1]\n\t"                               \
  "v_mul_f32 %[t2], %[t2], %[t2]\n\t"                               \
  "v_add_f32 %[t0], %[t0], %[t1]\n\t"                               \
  "v_add_f32 %[t0], %[t0], %[t2]\n\t"                               \
  "v_min_f32 %[pd" #j "], %[pd" #j "], %[t0]\n\t"                   \
  "v_cmp_le_f32 vcc, %[pd" #j "], %[lv]\n\t"                        \
  "v_max_f32 %[lv], %[lv], %[pd" #j "]\n\t"                         \
  "v_cndmask_b32 %[js], " #j ", %[js], vcc\n\t"

// one DPP max round (single VALU instruction; s_nop covers VALU->DPP hazard)
#define DPPR(op, v, ctrl)                                                        \
  #op " %[" #v "], %[" #v "], %[" #v "] " ctrl                                   \
  " row_mask:0xf bank_mask:0xf bound_ctrl:0\n\t"                                 \
  "s_nop 1\n\t"

  int far = 0;
  int h0 = 0, h1 = 0, h2 = 0, h3 = 0;  // far-at-entry of steps tid+k*512
  for (int s = 0; s < NPOINT_ - 1; ++s) {
    const float4 c = cP[far];                    // one b128 broadcast read
    const float cx = c.x, cy = c.y, cz = c.z;

    float lv = 0.0f;
    int js = 0;
    float t0, t1, t2;
    asm volatile(
        UPDASM(0) UPDASM(1) UPDASM(2) UPDASM(3)
        UPDASM(4) UPDASM(5) UPDASM(6) UPDASM(7)
        UPDASM(8) UPDASM(9) UPDASM(10) UPDASM(11)
        UPDASM(12) UPDASM(13) UPDASM(14) UPDASM(15)
        : [pd0] "+v"(pD0), [pd1] "+v"(pD1), [pd2] "+v"(pD2), [pd3] "+v"(pD3),
          [pd4] "+v"(pD4), [pd5] "+v"(pD5), [pd6] "+v"(pD6), [pd7] "+v"(pD7),
          [pd8] "+v"(pD8), [pd9] "+v"(pD9), [pd10] "+v"(pD10), [pd11] "+v"(pD11),
          [pd12] "+v"(pD12), [pd13] "+v"(pD13), [pd14] "+v"(pD14), [pd15] "+v"(pD15),
          [lv] "+v"(lv), [js] "+v"(js),
          [t0] "=&v"(t0), [t1] "=&v"(t1), [t2] "=&v"(t2)
        : [px0] "v"(pX0), [py0] "v"(pY0), [pz0] "v"(pZ0),
          [px1] "v"(pX1), [py1] "v"(pY1), [pz1] "v"(pZ1),
          [px2] "v"(pX2), [py2] "v"(pY2), [pz2] "v"(pZ2),
          [px3] "v"(pX3), [py3] "v"(pY3), [pz3] "v"(pZ3),
          [px4] "v"(pX4), [py4] "v"(pY4), [pz4] "v"(pZ4),
          [px5] "v"(pX5), [py5] "v"(pY5), [pz5] "v"(pZ5),
          [px6] "v"(pX6), [py6] "v"(pY6), [pz6] "v"(pZ6),
          [px7] "v"(pX7), [py7] "v"(pY7), [pz7] "v"(pZ7),
          [px8] "v"(pX8), [py8] "v"(pY8), [pz8] "v"(pZ8),
          [px9] "v"(pX9), [py9] "v"(pY9), [pz9] "v"(pZ9),
          [px10] "v"(pX10), [py10] "v"(pY10), [pz10] "v"(pZ10),
          [px11] "v"(pX11), [py11] "v"(pY11), [pz11] "v"(pZ11),
          [px12] "v"(pX12), [py12] "v"(pY12), [pz12] "v"(pZ12),
          [px13] "v"(pX13), [py13] "v"(pY13), [pz13] "v"(pZ13),
          [px14] "v"(pX14), [py14] "v"(pY14), [pz14] "v"(pZ14),
          [px15] "v"(pX15), [py15] "v"(pY15), [pz15] "v"(pZ15),
          [cx] "v"(cx), [cy] "v"(cy), [cz] "v"(cz)
        : "vcc");
    const int li13 = 8191 - (tid + (js << 9));

    // DPP wave reduce: copy lv -> 6 single-instr max rounds -> lane63 = M;
    // readlane M; key = (lv==M) ? 8191-li : 0; 6 u32 max rounds -> lane63 =
    // max key = min index among ties.
    int smi;          // wave-max float bits (uniform via SGPR)
    int key = 0;
    float red;
    asm volatile(
        "v_mov_b32 %[red], %[lv]\n\t"
        "s_nop 1\n\t"
        DPPR(v_max_f32, red, "row_ror:1")
        DPPR(v_max_f32, red, "row_ror:2")
        DPPR(v_max_f32, red, "row_ror:4")
        DPPR(v_max_f32, red, "row_ror:8")
        DPPR(v_max_f32, red, "row_bcast:15")
        DPPR(v_max_f32, red, "row_bcast:31")
        "s_nop 3\n\t"
        "v_readlane_b32 %[sm], %[red], 63\n\t"
        "s_nop 3\n\t"
        "v_cmp_eq_f32 vcc, %[sm], %[lv]\n\t"
        "v_cndmask_b32 %[key], 0, %[li13], vcc\n\t"
        "s_nop 1\n\t"
        DPPR(v_max_u32, key, "row_ror:1")
        DPPR(v_max_u32, key, "row_ror:2")
        DPPR(v_max_u32, key, "row_ror:4")
        DPPR(v_max_u32, key, "row_ror:8")
        DPPR(v_max_u32, key, "row_bcast:15")
        DPPR(v_max_u32, key, "row_bcast:31")
        : [red] "=&v"(red), [sm] "=&s"(smi), [key] "+v"(key)
        : [lv] "v"(lv), [li13] "v"(li13)
        : "vcc");

    if (lane == 63) {
      // pack: [55:45]=step (monotone -> no slot reset), [44:13]=dist bits
      // (nonneg f32, order-preserving), [12:0]=8191-idx (min index wins).
      const unsigned long long pk = ((unsigned long long)s << 45) |
                                    ((unsigned long long)(unsigned)smi << 13) |
                                    (unsigned)key;
      atomicMax(&slot[s & 1], pk);
    }
    __syncthreads();
    far = 8191 - (int)(slot[s & 1] & 0x1FFFull);

    const int d = s + 1 - tid;
    if (d == 0) h0 = far;
    if (d == 512) h1 = far;
    if (d == 1024) h2 = far;
    if (d == 1536) h3 = far;
  }
#undef UPDASM
#undef DPPR

  // epilogue: thread t writes centroids for steps t, t+512, t+1024, t+1536
  {
#define WOUT(k, hh)                                                   \
    {                                                                 \
      const int ss = tid + (k) * FT;                                  \
      const float4 cc = cP[hh];                                       \
      nxT[(size_t)(b * NPOINT_ + ss) * 3 + 0] = cc.x;                 \
      nxT[(size_t)(b * NPOINT_ + ss) * 3 + 1] = cc.y;                 \
      nxT[(size_t)(b * NPOINT_ + ss) * 3 + 2] = cc.z;                 \
      out0[((size_t)b * 3 + 0) * NPOINT_ + ss] = cc.x;                \
      out0[((size_t)b * 3 + 1) * NPOINT_ + ss] = cc.y;                \
      out0[((size_t)b * 3 + 2) * NPOINT_ + ss] = cc.z;                \
    }
    WOUT(0, h0) WOUT(1, h1) WOUT(2, h2) WOUT(3, h3)
#undef WOUT
  }
}

// ---------------------------------------------------------------------------
// K2: ball query. One wave per centroid; first 32 in-radius indices in
// ascending index order via ballot ranks, early exit, pad with first.
// ---------------------------------------------------------------------------
__global__ __launch_bounds__(256) void k_ballquery(const float* __restrict__ xyz,
                                                   const float* __restrict__ nxT,
                                                   int* __restrict__ gidx) {
  const int wid = (int)((blockIdx.x * 256 + threadIdx.x) >> 6);
  const int lane = threadIdx.x & 63;
  const int b = wid >> 11;                 // / NPOINT
  const float* xb = xyz + (size_t)b * 3 * N_;
  const float cx = nxT[(size_t)wid * 3 + 0];
  const float cy = nxT[(size_t)wid * 3 + 1];
  const float cz = nxT[(size_t)wid * 3 + 2];
  int* out = gidx + (size_t)wid * NSAMPLE_;

  int count = 0, first = 0;
  for (int ch = 0; ch < N_ / 64; ++ch) {
    const int j = ch * 64 + lane;
    const float dx = xb[j] - cx, dy = xb[N_ + j] - cy, dz = xb[2 * N_ + j] - cz;
    const float d2 = __fadd_rn(__fadd_rn(__fmul_rn(dx, dx), __fmul_rn(dy, dy)),
                               __fmul_rn(dz, dz));
    const bool in = (d2 <= 0.16f);         // 0.16f == f32(0.4*0.4), exact match
    const unsigned long long mask = __ballot(in);
    if (mask) {
      if (count == 0) first = ch * 64 + (__ffsll((long long)mask) - 1);
      if (in) {
        const int rank = count + __popcll(mask & ((1ull << lane) - 1ull));
        if (rank < NSAMPLE_) out[rank] = j;
      }
      count += __popcll(mask);
      if (count >= NSAMPLE_) break;
    }
  }
  if (count < NSAMPLE_ && lane >= count && lane < NSAMPLE_) out[lane] = first;
}

// ---------------------------------------------------------------------------
// K3/K5: gather + MLP, software-pipelined (T14): group i+1's gather staged in
// registers during group i's compute; gidx read directly (L1 broadcast).
// PHASE 1: layer-1 partial BN stats. PHASE 2: layer-1 (folded BN) + layer-2;
// emits layer-2 partial BN stats AND per-(group,channel) max/min of raw y2
// (max-pool commutes with the monotone affine+relu epilogue).
// ---------------------------------------------------------------------------
template <int PHASE>
__global__ __launch_bounds__(256) void k_mlp(
    const float* __restrict__ xyz, const float* __restrict__ featT,
    const float* __restrict__ nxT, const int* __restrict__ gidx,
    const float* __restrict__ w1, const float* __restrict__ b1,
    const float* __restrict__ w2, const float* __restrict__ b2,
    const float* __restrict__ ac1,
    float* __restrict__ part, float* __restrict__ maxb, float* __restrict__ minb) {
  __shared__ float xs[32][36];
  __shared__ float w1s[64 * 35];
  __shared__ __align__(16) float w2cm[64 * 128];  // c-major [c][o]
  __shared__ __align__(16) float x2s[32 * 64];
  __shared__ float pbuf[2048];

  const int t = threadIdx.x;
  for (int i = t; i < 64 * 35; i += 256) w1s[i] = w1[i];
  if constexpr (PHASE == 2) {
    for (int i = t; i < 64 * 128; i += 256) {
      const int c = i >> 7, o = i & 127;
      w2cm[i] = w2[o * 64 + c];
    }
  }
  const int o2 = t & 31, kq = t >> 5;
  const int gk = t >> 3, gq = t & 7;   // gather: sample gk, float4 slot gq

  float bb1[2];
  float a1r[2] = {0.f, 0.f}, c1r[2] = {0.f, 0.f};
  float bb2[4] = {0.f, 0.f, 0.f, 0.f};
#pragma unroll
  for (int q = 0; q < 2; q++) bb1[q] = b1[o2 * 2 + q];
  if constexpr (PHASE == 2) {
#pragma unroll
    for (int q = 0; q < 2; q++) { a1r[q] = ac1[o2 * 2 + q]; c1r[q] = ac1[64 + o2 * 2 + q]; }
#pragma unroll
    for (int q = 0; q < 4; q++) bb2[q] = b2[o2 * 4 + q];
  }

  float s1a[2] = {0.f, 0.f}, s1q[2] = {0.f, 0.f};
  float s2a[4] = {0.f, 0.f, 0.f, 0.f}, s2q[4] = {0.f, 0.f, 0.f, 0.f};

  // ---- prologue: stage group 0 into registers
  float4 fpre;
  float xpx = 0.f, xpy = 0.f, xpz = 0.f;
  {
    const int G = blockIdx.x * 8;
    const int b = G >> 11;
    const int j = gidx[(size_t)G * NSAMPLE_ + gk];
    fpre = *(const float4*)(featT + ((size_t)(b * N_ + j)) * DIN_ + gq * 4);
    if (t < 32) {
      const int j2 = gidx[(size_t)G * NSAMPLE_ + t];
      const float* xb = xyz + (size_t)b * 3 * N_;
      xpx = xb[j2] - nxT[(size_t)G * 3 + 0];
      xpy = xb[N_ + j2] - nxT[(size_t)G * 3 + 1];
      xpz = xb[2 * N_ + j2] - nxT[(size_t)G * 3 + 2];
    }
  }

  for (int i = 0; i < 8; i++) {
    const int G = blockIdx.x * 8 + i;
    __syncthreads();   // xs free (previous group's compute done)
    // commit staged registers -> LDS
    xs[gk][3 + gq * 4 + 0] = fpre.x;
    xs[gk][3 + gq * 4 + 1] = fpre.y;
    xs[gk][3 + gq * 4 + 2] = fpre.z;
    xs[gk][3 + gq * 4 + 3] = fpre.w;
    if (t < 32) { xs[t][0] = xpx; xs[t][1] = xpy; xs[t][2] = xpz; }
    // issue next group's gather (overlaps this group's compute)
    if (i < 7) {
      const int Gn = G + 1;
      const int bn = Gn >> 11;
      const int jn = gidx[(size_t)Gn * NSAMPLE_ + gk];
      fpre = *(const float4*)(featT + ((size_t)(bn * N_ + jn)) * DIN_ + gq * 4);
      if (t < 32) {
        const int j2 = gidx[(size_t)Gn * NSAMPLE_ + t];
        const float* xb = xyz + (size_t)bn * 3 * N_;
        xpx = xb[j2] - nxT[(size_t)Gn * 3 + 0];
        xpy = xb[N_ + j2] - nxT[(size_t)Gn * 3 + 1];
        xpz = xb[2 * N_ + j2] - nxT[(size_t)Gn * 3 + 2];
      }
    }
    __syncthreads();

    // layer 1: y1[k][o], thread tile 4k x 2o
    float acc[4][2];
#pragma unroll
    for (int r = 0; r < 4; r++) { acc[r][0] = bb1[0]; acc[r][1] = bb1[1]; }
#pragma unroll
    for (int c = 0; c < 35; c++) {
      float xv[4];
#pragma unroll
      for (int r = 0; r < 4; r++) xv[r] = xs[kq * 4 + r][c];
      float wv[2];
      wv[0] = w1s[(o2 * 2 + 0) * 35 + c];
      wv[1] = w1s[(o2 * 2 + 1) * 35 + c];
#pragma unroll
      for (int r = 0; r < 4; r++) { acc[r][0] += xv[r] * wv[0]; acc[r][1] += xv[r] * wv[1]; }
    }

    if constexpr (PHASE == 1) {
#pragma unroll
      for (int q = 0; q < 2; q++)
#pragma unroll
        for (int r = 0; r < 4; r++) {
          const float v = acc[r][q];
          s1a[q] += v;
          s1q[q] += v * v;
        }
    } else {
#pragma unroll
      for (int r = 0; r < 4; r++)
#pragma unroll
        for (int q = 0; q < 2; q++) {
          float v = acc[r][q] * a1r[q] + c1r[q];
          v = fmaxf(v, 0.f);
          x2s[(kq * 4 + r) * 64 + o2 * 2 + q] = v;
        }
      __syncthreads();

      // layer 2: y2[k][o], thread tile 4k x 4o, float4 LDS reads
      float a2[4][4];
#pragma unroll
      for (int r = 0; r < 4; r++)
#pragma unroll
        for (int q = 0; q < 4; q++) a2[r][q] = bb2[q];
#pragma unroll 4
      for (int cc4 = 0; cc4 < 16; cc4++) {
        float4 xv4[4];
#pragma unroll
        for (int r = 0; r < 4; r++) xv4[r] = *(const float4*)&x2s[(kq * 4 + r) * 64 + cc4 * 4];
        float4 wv4[4];
#pragma unroll
        for (int cq = 0; cq < 4; cq++) wv4[cq] = *(const float4*)&w2cm[(cc4 * 4 + cq) * 128 + o2 * 4];
#pragma unroll
        for (int cq = 0; cq < 4; cq++) {
#pragma unroll
          for (int r = 0; r < 4; r++) {
            const float xr = ((const float*)&xv4[r])[cq];
#pragma unroll
            for (int q = 0; q < 4; q++) a2[r][q] += xr * ((const float*)&wv4[cq])[q];
          }
        }
      }

      // BN2 stats
#pragma unroll
      for (int q = 0; q < 4; q++)
#pragma unroll
        for (int r = 0; r < 4; r++) {
          const float v = a2[r][q];
          s2a[q] += v;
          s2q[q] += v * v;
        }
      // per-group max/min of raw y2 over the 32 samples
      float mx[4], mn[4];
#pragma unroll
      for (int q = 0; q < 4; q++) { mx[q] = a2[0][q]; mn[q] = a2[0][q]; }
#pragma unroll
      for (int r = 1; r < 4; r++)
#pragma unroll
        for (int q = 0; q < 4; q++) {
          mx[q] = fmaxf(mx[q], a2[r][q]);
          mn[q] = fminf(mn[q], a2[r][q]);
        }
#pragma unroll
      for (int q = 0; q < 4; q++) {
        pbuf[kq * 128 + o2 * 4 + q] = mx[q];
        pbuf[1024 + kq * 128 + o2 * 4 + q] = mn[q];
      }
      __syncthreads();
      if (t < 128) {
        float MX = pbuf[t], MN = pbuf[1024 + t];
#pragma unroll
        for (int kk = 1; kk < 8; kk++) {
          MX = fmaxf(MX, pbuf[kk * 128 + t]);
          MN = fminf(MN, pbuf[1024 + kk * 128 + t]);
        }
        maxb[(size_t)G * 128 + t] = MX;
        minb[(size_t)G * 128 + t] = MN;
      }
    }
  }

  // deterministic block-level stat dump
  if constexpr (PHASE == 1) {
    __syncthreads();
#pragma unroll
    for (int q = 0; q < 2; q++) {
      pbuf[(o2 * 2 + q) * 8 + kq] = s1a[q];
      pbuf[512 + (o2 * 2 + q) * 8 + kq] = s1q[q];
    }
    __syncthreads();
    if (t < 64) {
      float S = 0.f, Q = 0.f;
#pragma unroll
      for (int kk = 0; kk < 8; kk++) { S += pbuf[t * 8 + kk]; Q += pbuf[512 + t * 8 + kk]; }
      part[(size_t)blockIdx.x * 128 + t * 2 + 0] = S;
      part[(size_t)blockIdx.x * 128 + t * 2 + 1] = Q;
    }
  }
  if constexpr (PHASE == 2) {
    __syncthreads();
#pragma unroll
    for (int q = 0; q < 4; q++) {
      pbuf[(o2 * 4 + q) * 8 + kq] = s2a[q];
      pbuf[1024 + (o2 * 4 + q) * 8 + kq] = s2q[q];
    }
    __syncthreads();
    if (t < 128) {
      float S = 0.f, Q = 0.f;
#pragma unroll
      for (int kk = 0; kk < 8; kk++) { S += pbuf[t * 8 + kk]; Q += pbuf[1024 + t * 8 + kk]; }
      part[(size_t)blockIdx.x * 256 + t * 2 + 0] = S;
      part[(size_t)blockIdx.x * 256 + t * 2 + 1] = Q;
    }
  }
}

// ---------------------------------------------------------------------------
// K4/K6: reduce block partials -> BN scale/bias. 1024 threads.
// Fixed-order (deterministic).
// ---------------------------------------------------------------------------
__global__ __launch_bounds__(1024) void k_stats1(const float* __restrict__ part,
                                                 const float* __restrict__ g,
                                                 const float* __restrict__ be,
                                                 float* __restrict__ ac) {
  const int t = threadIdx.x;
  const int ch = t & 63, sl = t >> 6;  // 16 slices
  float s = 0.f, q = 0.f;
  for (int bk = sl; bk < 2048; bk += 16) {
    s += part[(size_t)bk * 128 + ch * 2 + 0];
    q += part[(size_t)bk * 128 + ch * 2 + 1];
  }
  __shared__ float ss[16][64], qs[16][64];
  ss[sl][ch] = s;
  qs[sl][ch] = q;
  __syncthreads();
  if (t < 64) {
    float S = 0.f, Q = 0.f;
#pragma unroll
    for (int k = 0; k < 16; k++) { S += ss[k][t]; Q += qs[k][t]; }
    const float mu = S / (float)TOT_;
    const float var = Q / (float)TOT_ - mu * mu;
    const float a = g[t] * (1.0f / sqrtf(var + EPS_));
    ac[t] = a;
    ac[64 + t] = be[t] - mu * a;
  }
}

__global__ __launch_bounds__(1024) void k_stats2(const float* __restrict__ part,
                                                 const float* __restrict__ g,
                                                 const float* __restrict__ be,
                                                 float* __restrict__ ac) {
  const int t = threadIdx.x;
  const int ch = t & 127, sl = t >> 7;  // 8 slices
  float s = 0.f, q = 0.f;
  for (int bk = sl; bk < 2048; bk += 8) {
    s += part[(size_t)bk * 256 + ch * 2 + 0];
    q += part[(size_t)bk * 256 + ch * 2 + 1];
  }
  __shared__ float ss[8][128], qs[8][128];
  ss[sl][ch] = s;
  qs[sl][ch] = q;
  __syncthreads();
  if (t < 128) {
    float S = 0.f, Q = 0.f;
#pragma unroll
    for (int k = 0; k < 8; k++) { S += ss[k][t]; Q += qs[k][t]; }
    const float mu = S / (float)TOT_;
    const float var = Q / (float)TOT_ - mu * mu;
    const float a = g[t] * (1.0f / sqrtf(var + EPS_));
    ac[t] = a;
    ac[128 + t] = be[t] - mu * a;
  }
}

// ---------------------------------------------------------------------------
// K7: finalize. out1[b][ch][s] = relu(a2[ch]*(a2>=0 ? max : min) + c2[ch]).
// LDS transpose so both the minmax reads and the out1 writes are coalesced.
// ---------------------------------------------------------------------------
__global__ __launch_bounds__(256) void k_finalize(const float* __restrict__ maxb,
                                                  const float* __restrict__ minb,
                                                  const float* __restrict__ ac2,
                                                  float* __restrict__ out1) {
  __shared__ float tile[128][33];
  const int b = blockIdx.x >> 6;
  const int s0 = (blockIdx.x & 63) * 32;
  const int t = threadIdx.x;
#pragma unroll
  for (int it = 0; it < 16; ++it) {
    const int idx = it * 256 + t;
    const int sl = idx >> 7, ch = idx & 127;
    const size_t G = (size_t)b * NPOINT_ + s0 + sl;
    const float a = ac2[ch], c = ac2[128 + ch];
    const float y = (a >= 0.f) ? maxb[G * 128 + ch] : minb[G * 128 + ch];
    tile[ch][sl] = fmaxf(y * a + c, 0.f);
  }
  __syncthreads();
#pragma unroll
  for (int it = 0; it < 16; ++it) {
    const int idx = it * 256 + t;
    const int ch = idx >> 5, sl = idx & 31;
    out1[((size_t)(b * C2_ + ch)) * NPOINT_ + s0 + sl] = tile[ch][sl];
  }
}

// ---------------------------------------------------------------------------
extern "C" void kernel_launch(void* const* d_in, const int* in_sizes, int n_in,
                              void* d_out, int out_size, void* d_ws, size_t ws_size,
                              hipStream_t stream) {
  const float* xyz = (const float*)d_in[0];
  const float* pts = (const float*)d_in[1];
  const float* w1 = (const float*)d_in[2];
  const float* b1 = (const float*)d_in[3];
  const float* g1 = (const float*)d_in[4];
  const float* be1 = (const float*)d_in[5];
  const float* w2 = (const float*)d_in[6];
  const float* b2 = (const float*)d_in[7];
  const float* g2 = (const float*)d_in[8];
  const float* be2 = (const float*)d_in[9];

  float* out0 = (float*)d_out;
  float* out1 = out0 + (size_t)B_ * 3 * NPOINT_;

  float* wsf = (float*)d_ws;
  float* featT = wsf;                                    // B*N*32 = 2097152
  float* nxT = featT + (size_t)B_ * N_ * DIN_;           // B*NPOINT*3 = 49152
  float* part1 = nxT + (size_t)B_ * NPOINT_ * 3;         // 2048*128
  float* part2 = part1 + (size_t)2048 * 128;             // 2048*256
  float* ac1 = part2 + (size_t)2048 * 256;               // 128
  float* ac2 = ac1 + 128;                                // 256
  float* maxb = ac2 + 256;                               // 16384*128
  float* minb = maxb + (size_t)B_ * NPOINT_ * 128;       // 16384*128
  int* gidx = (int*)(minb + (size_t)B_ * NPOINT_ * 128); // B*NPOINT*32 ints

  k_fps_tr<<<dim3(256), dim3(FT), 0, stream>>>(xyz, pts, featT, nxT, out0);
  k_ballquery<<<dim3(B_ * NPOINT_ / 4), dim3(256), 0, stream>>>(xyz, nxT, gidx);
  k_mlp<1><<<dim3(2048), dim3(256), 0, stream>>>(xyz, featT, nxT, gidx, w1, b1, w2, b2,
                                                 nullptr, part1, nullptr, nullptr);
  k_stats1<<<dim3(1), dim3(1024), 0, stream>>>(part1, g1, be1, ac1);
  k_mlp<2><<<dim3(2048), dim3(256), 0, stream>>>(xyz, featT, nxT, gidx, w1, b1, w2, b2,
                                                 ac1, part2, maxb, minb);
  k_stats2<<<dim3(1), dim3(1024), 0, stream>>>(part2, g2, be2, ac2);
  k_finalize<<<dim3(B_ * (NPOINT_ / 32)), dim3(256), 0, stream>>>(maxb, minb, ac2, out1);
}